// Round 10
// baseline (738.611 us; speedup 1.0000x reference)
//
#include <hip/hip_runtime.h>
#include <hip/hip_bf16.h>
#include <math.h>

#define CDIM 384
#define NW 49
#define NHEADS 12
#define HDIM 32
#define LROW 784
#define NROWS 50176        // B*L
#define MLPH 1536
#define QKVD 1152
#define MHALF 25088        // NROWS/2, for MLP half-passes

typedef __hip_bfloat16 bf16;
typedef __attribute__((ext_vector_type(8))) short bf16x8;   // 8 bf16 = 4 VGPR
typedef __attribute__((ext_vector_type(4))) short short4v;  // 4 bf16 = 8B
typedef __attribute__((ext_vector_type(4))) float f32x4;

__device__ __forceinline__ float b2f(bf16 v) { return __bfloat162float(v); }
__device__ __forceinline__ bf16 f2b(float v) { return __float2bfloat16(v); }
__device__ __forceinline__ unsigned short fbits(float v) {
  bf16 t = f2b(v);
  return *(unsigned short*)&t;
}

// ---------------- sentinel fill (fp32) ----------------
__global__ __launch_bounds__(256) void k_fill(float* out, int n, float val) {
  int i = blockIdx.x * 256 + threadIdx.x;
  if (i < n) out[i] = val;
}

// ---------------- fp32 -> bf16 weight convert ----------------
__global__ __launch_bounds__(256) void k_f2b(const float* __restrict__ in,
                                             bf16* __restrict__ out, int n) {
  int i = blockIdx.x * 256 + threadIdx.x;
  if (i < n) out[i] = f2b(in[i]);
}

// ---------------- precompute dense attn bias table ----------------
__global__ __launch_bounds__(256) void k_biast(const float* __restrict__ attn_bias,
                                               const int* __restrict__ bias_idxs,
                                               int noff, float* __restrict__ biasT) {
  int t = blockIdx.x * 256 + threadIdx.x;
  if (t >= NHEADS * 64 * 64) return;
  int j = t & 3, fr = (t >> 2) & 15, n = (t >> 6) & 63, h = t >> 12;
  int m = j * 16 + fr;
  float v = -1e30f;
  if (n < NW && m < NW) v = attn_bias[h * noff + bias_idxs[n * NW + m]];
  biasT[t] = v;
}

// ---------------- LayerNorm -> bf16, scattered to window-row order ----------------
__global__ __launch_bounds__(256) void k_ln_win(const float* __restrict__ in,
                                                const float* __restrict__ g,
                                                const float* __restrict__ b,
                                                bf16* __restrict__ outp) {
  __shared__ float s1[256], s2[256];
  const int tid = threadIdx.x;
  const int rg = blockIdx.x;
  const float* row = in + (size_t)rg * CDIM;
  float a = row[tid];
  float c2 = (tid < CDIM - 256) ? row[tid + 256] : 0.f;
  s1[tid] = a + c2;
  s2[tid] = a * a + c2 * c2;
  __syncthreads();
  for (int s = 128; s > 0; s >>= 1) {
    if (tid < s) { s1[tid] += s1[tid + s]; s2[tid] += s2[tid + s]; }
    __syncthreads();
  }
  const float mean = s1[0] * (1.f / CDIM);
  const float var = s2[0] * (1.f / CDIM) - mean * mean;
  const float inv = rsqrtf(var + 1e-5f);
  int bb = rg / LROW, l = rg - bb * LROW;
  int hs = l / 28, ws = l - hs * 28;
  int wi = hs / 7, r7 = hs - wi * 7, wj = ws / 7, s7 = ws - wj * 7;
  int wrow = (bb * 16 + wi * 4 + wj) * NW + r7 * 7 + s7;
  bf16* orow = outp + (size_t)wrow * CDIM;
  orow[tid] = f2b((row[tid] - mean) * inv * g[tid] + b[tid]);
  if (tid < CDIM - 256)
    orow[tid + 256] = f2b((row[tid + 256] - mean) * inv * g[tid + 256] + b[tid + 256]);
}

// ---------------- MFMA GEMM core v2: C[128x128] += A[128xK] * W[128xK]^T ----------------
// BK=64, global_load_lds width-16 staging, both-sides XOR swizzle (guideline 21).
template<int K>
__device__ __forceinline__ void gemm_tile(const bf16* __restrict__ A,
                                          const bf16* __restrict__ W,
                                          int arow0, int brow0, f32x4 acc[4][4]) {
  __shared__ __align__(16) unsigned short As[128 * 64];
  __shared__ __align__(16) unsigned short Bs[128 * 64];
  const int tid = threadIdx.x;
  const int lane = tid & 63;
  const int wid = tid >> 6;
  const int wr = wid >> 1, wc = wid & 1;       // wave position in 2x2
  const int fr = lane & 15, kg = lane >> 4;    // fragment row, k-group
  const int srow = wid * 32 + (lane >> 3);
  const int scol = (((lane & 7) ^ ((lane >> 3) & 7)) * 8);  // swizzled source col (elems)
  for (int kt = 0; kt < K; kt += 64) {
    if (kt) __syncthreads();   // prior iter's LDS reads done before overwrite
#pragma unroll
    for (int i = 0; i < 4; ++i) {
      __builtin_amdgcn_global_load_lds(
          (const __attribute__((address_space(1))) void*)(A + (size_t)(arow0 + srow + i * 8) * K + kt + scol),
          (__attribute__((address_space(3))) void*)(&As[(wid * 32 + i * 8) * 64]), 16, 0, 0);
      __builtin_amdgcn_global_load_lds(
          (const __attribute__((address_space(1))) void*)(W + (size_t)(brow0 + srow + i * 8) * K + kt + scol),
          (__attribute__((address_space(3))) void*)(&Bs[(wid * 32 + i * 8) * 64]), 16, 0, 0);
    }
    __syncthreads();           // drains vmcnt(0): tiles resident
#pragma unroll
    for (int kk = 0; kk < 2; ++kk) {
      const int slot = ((kk * 4 + kg) ^ (fr & 7)) * 8;
      bf16x8 af[4], bv[4];
#pragma unroll
      for (int i = 0; i < 4; ++i) {
        af[i] = *(const bf16x8*)(&As[(wr * 64 + i * 16 + fr) * 64 + slot]);
        bv[i] = *(const bf16x8*)(&Bs[(wc * 64 + i * 16 + fr) * 64 + slot]);
      }
#pragma unroll
      for (int i = 0; i < 4; ++i)
#pragma unroll
        for (int j = 0; j < 4; ++j)
          acc[i][j] = __builtin_amdgcn_mfma_f32_16x16x32_bf16(af[i], bv[j], acc[i][j], 0, 0, 0);
    }
  }
}

// ---------------- MFMA GEMM core v2-narrow: C[128x64] += A[128xK] * W[64xK]^T ----------------
// Same staging/swizzle scheme, B-tile 64 rows (2 gload_lds calls), wave-tile 64x32.
// Used by k_gfc2 (N=384 -> 6 col-tiles -> 1176 blocks = 4.6/CU vs 2.3 at BN=128).
template<int K>
__device__ __forceinline__ void gemm_tile64(const bf16* __restrict__ A,
                                            const bf16* __restrict__ W,
                                            int arow0, int brow0, f32x4 acc[4][2]) {
  __shared__ __align__(16) unsigned short As[128 * 64];
  __shared__ __align__(16) unsigned short Bs[64 * 64];
  const int tid = threadIdx.x;
  const int lane = tid & 63;
  const int wid = tid >> 6;
  const int wr = wid >> 1, wc = wid & 1;       // wave position in 2x2
  const int fr = lane & 15, kg = lane >> 4;
  const int srowA = wid * 32 + (lane >> 3);    // + i*8, i=0..3
  const int srowB = wid * 16 + (lane >> 3);    // + i*8, i=0..1
  const int scol = (((lane & 7) ^ ((lane >> 3) & 7)) * 8);
  for (int kt = 0; kt < K; kt += 64) {
    if (kt) __syncthreads();
#pragma unroll
    for (int i = 0; i < 4; ++i)
      __builtin_amdgcn_global_load_lds(
          (const __attribute__((address_space(1))) void*)(A + (size_t)(arow0 + srowA + i * 8) * K + kt + scol),
          (__attribute__((address_space(3))) void*)(&As[(wid * 32 + i * 8) * 64]), 16, 0, 0);
#pragma unroll
    for (int i = 0; i < 2; ++i)
      __builtin_amdgcn_global_load_lds(
          (const __attribute__((address_space(1))) void*)(W + (size_t)(brow0 + srowB + i * 8) * K + kt + scol),
          (__attribute__((address_space(3))) void*)(&Bs[(wid * 16 + i * 8) * 64]), 16, 0, 0);
    __syncthreads();
#pragma unroll
    for (int kk = 0; kk < 2; ++kk) {
      const int slot = ((kk * 4 + kg) ^ (fr & 7)) * 8;
      bf16x8 af[4], bv[2];
#pragma unroll
      for (int i = 0; i < 4; ++i)
        af[i] = *(const bf16x8*)(&As[(wr * 64 + i * 16 + fr) * 64 + slot]);
#pragma unroll
      for (int j = 0; j < 2; ++j)
        bv[j] = *(const bf16x8*)(&Bs[(wc * 32 + j * 16 + fr) * 64 + slot]);
#pragma unroll
      for (int i = 0; i < 4; ++i)
#pragma unroll
        for (int j = 0; j < 2; ++j)
          acc[i][j] = __builtin_amdgcn_mfma_f32_16x16x32_bf16(af[i], bv[j], acc[i][j], 0, 0, 0);
    }
  }
}

#define GEMM_PROLOGUE(KK)                                                   \
  f32x4 acc[4][4];                                                          \
  for (int i = 0; i < 4; ++i)                                               \
    for (int j = 0; j < 4; ++j) acc[i][j] = (f32x4){0.f, 0.f, 0.f, 0.f};    \
  const int arow0 = blockIdx.x * 128, bcol0 = blockIdx.y * 128;             \
  gemm_tile<KK>(A, W, arow0, bcol0, acc);                                   \
  const int tid = threadIdx.x, lane = tid & 63, wid = tid >> 6;             \
  const int wr = wid >> 1, wc = wid & 1, fr = lane & 15, rq = lane >> 4;

// ---------------- QKV GEMM: out bf16 [wrow, 1152] ----------------
__global__ __launch_bounds__(256) void k_gqkv(const bf16* __restrict__ A,
                                              const bf16* __restrict__ W,
                                              const float* __restrict__ bias,
                                              bf16* __restrict__ out) {
  GEMM_PROLOGUE(CDIM)
#pragma unroll
  for (int i = 0; i < 4; ++i)
#pragma unroll
    for (int r = 0; r < 4; ++r) {
      int m = arow0 + wr * 64 + i * 16 + rq * 4 + r;
#pragma unroll
      for (int j = 0; j < 4; ++j) {
        int n = bcol0 + wc * 64 + j * 16 + fr;
        out[(size_t)m * QKVD + n] = f2b(acc[i][j][r] + bias[n]);
      }
    }
}

// ---------------- proj GEMM + bias + residual, scatter window->spatial ----------------
__global__ __launch_bounds__(256) void k_gproj(const bf16* __restrict__ A,
                                               const bf16* __restrict__ W,
                                               const float* __restrict__ bias,
                                               const float* __restrict__ xin,
                                               float* __restrict__ x1) {
  GEMM_PROLOGUE(CDIM)
#pragma unroll
  for (int i = 0; i < 4; ++i)
#pragma unroll
    for (int r = 0; r < 4; ++r) {
      int m = arow0 + wr * 64 + i * 16 + rq * 4 + r;   // window row
      int win = m / NW, nn = m - win * NW;
      int bb = win >> 4, wrem = win & 15, wi = wrem >> 2, wj = wrem & 3;
      int r7 = nn / 7, s7 = nn - r7 * 7;
      int l = (wi * 7 + r7) * 28 + wj * 7 + s7;
      size_t srow = (size_t)(bb * LROW + l) * CDIM;
#pragma unroll
      for (int j = 0; j < 4; ++j) {
        int n = bcol0 + wc * 64 + j * 16 + fr;
        x1[srow + n] = xin[srow + n] + acc[i][j][r] + bias[n];
      }
    }
}

// ---------------- FC1 GEMM + GELU: out bf16 [m,1536] ----------------
__global__ __launch_bounds__(256) void k_gfc1(const bf16* __restrict__ A,
                                              const bf16* __restrict__ W,
                                              const float* __restrict__ bias,
                                              bf16* __restrict__ out) {
  GEMM_PROLOGUE(CDIM)
#pragma unroll
  for (int i = 0; i < 4; ++i)
#pragma unroll
    for (int r = 0; r < 4; ++r) {
      int m = arow0 + wr * 64 + i * 16 + rq * 4 + r;
#pragma unroll
      for (int j = 0; j < 4; ++j) {
        int n = bcol0 + wc * 64 + j * 16 + fr;
        float v = acc[i][j][r] + bias[n];
        out[(size_t)m * MLPH + n] = f2b(0.5f * v * (1.f + erff(v * 0.70710678118654752f)));
      }
    }
}

// ---------------- FC2 GEMM + bias + residual, BN=64 tile, in-place on xout ----------------
__global__ __launch_bounds__(256) void k_gfc2(const bf16* __restrict__ A,
                                              const bf16* __restrict__ W,
                                              const float* __restrict__ bias,
                                              float* __restrict__ xout) {
  f32x4 acc[4][2];
  for (int i = 0; i < 4; ++i)
    for (int j = 0; j < 2; ++j) acc[i][j] = (f32x4){0.f, 0.f, 0.f, 0.f};
  const int arow0 = blockIdx.x * 128, bcol0 = blockIdx.y * 64;
  gemm_tile64<MLPH>(A, W, arow0, bcol0, acc);
  const int tid = threadIdx.x, lane = tid & 63, wid = tid >> 6;
  const int wr = wid >> 1, wc = wid & 1, fr = lane & 15, rq = lane >> 4;
#pragma unroll
  for (int i = 0; i < 4; ++i)
#pragma unroll
    for (int r = 0; r < 4; ++r) {
      int m = arow0 + wr * 64 + i * 16 + rq * 4 + r;
#pragma unroll
      for (int j = 0; j < 2; ++j) {
        int n = bcol0 + wc * 32 + j * 16 + fr;
        size_t dst = (size_t)m * CDIM + n;
        xout[dst] = xout[dst] + acc[i][j][r] + bias[n];
      }
    }
}

// ---------------- attention v3: one WAVE per (win, head), dense bias table ----------------
__global__ __launch_bounds__(256) void k_attn2(const bf16* __restrict__ qkv,
                                               const float* __restrict__ biasT,
                                               bf16* __restrict__ outp) {
  __shared__ __align__(16) unsigned short Psh[4][64][72];
  const int tid = threadIdx.x;
  const int wid = tid >> 6, lane = tid & 63;
  const int fr = lane & 15, kg = lane >> 4;
  const int gid = blockIdx.x * 4 + wid;          // win*NHEADS + h
  const int win = gid / NHEADS, h = gid - win * NHEADS;
  const bf16* base = qkv + (size_t)win * NW * QKVD + h * 96;  // q|k|v 32-col slices

  // ---- QK^T ----
  const bf16x8 zero8 = {0, 0, 0, 0, 0, 0, 0, 0};
  bf16x8 qf[4], kf[4];
#pragma unroll
  for (int i = 0; i < 4; ++i) {
    int rr = i * 16 + fr;
    qf[i] = (rr < NW) ? *(const bf16x8*)(base + (size_t)rr * QKVD + kg * 8) : zero8;
    kf[i] = (rr < NW) ? *(const bf16x8*)(base + (size_t)rr * QKVD + 32 + kg * 8) : zero8;
  }
  f32x4 s[4][4];
#pragma unroll
  for (int i = 0; i < 4; ++i)
#pragma unroll
    for (int j = 0; j < 4; ++j)
      s[i][j] = (f32x4){0.f, 0.f, 0.f, 0.f};
#pragma unroll
  for (int i = 0; i < 4; ++i)
#pragma unroll
    for (int j = 0; j < 4; ++j)
      s[i][j] = __builtin_amdgcn_mfma_f32_16x16x32_bf16(qf[i], kf[j], s[i][j], 0, 0, 0);

  // ---- bias (one f32x4 per row from dense table) + softmax ----
  const float scale = 0.17677669529663687f;
  const float* btab = biasT + (((size_t)h * 64) * 16 + fr) * 4;
  float rsum[4][4];
#pragma unroll
  for (int i = 0; i < 4; ++i)
#pragma unroll
    for (int r = 0; r < 4; ++r) {
      int n = i * 16 + kg * 4 + r;
      f32x4 b4 = *(const f32x4*)(btab + (size_t)n * 64);
      float mx = -1e30f;
#pragma unroll
      for (int j = 0; j < 4; ++j) {
        float v = s[i][j][r] * scale + b4[j];
        s[i][j][r] = v;
        mx = fmaxf(mx, v);
      }
#pragma unroll
      for (int msk = 1; msk < 16; msk <<= 1) mx = fmaxf(mx, __shfl_xor(mx, msk));
      float sum = 0.f;
#pragma unroll
      for (int j = 0; j < 4; ++j) {
        float e = __expf(s[i][j][r] - mx);
        s[i][j][r] = e;
        sum += e;
      }
#pragma unroll
      for (int msk = 1; msk < 16; msk <<= 1) sum += __shfl_xor(sum, msk);
      rsum[i][r] = sum;
    }

  // ---- P -> LDS (bf16) ----
#pragma unroll
  for (int i = 0; i < 4; ++i)
#pragma unroll
    for (int r = 0; r < 4; ++r) {
      int n = i * 16 + kg * 4 + r;
#pragma unroll
      for (int j = 0; j < 4; ++j) {
        Psh[wid][n][j * 16 + fr] = fbits(s[i][j][r]);
      }
    }
  __syncthreads();

  // ---- V^T fragments ----
  bf16x8 vf[2][2];  // [d-tile j][k-tile kt]
#pragma unroll
  for (int j = 0; j < 2; ++j)
#pragma unroll
    for (int kt = 0; kt < 2; ++kt)
#pragma unroll
      for (int e = 0; e < 8; ++e) {
        int m = kt * 32 + kg * 8 + e;
        bf16 val = (m < NW) ? base[(size_t)m * QKVD + 64 + j * 16 + fr] : f2b(0.f);
        vf[j][kt][e] = *(short*)&val;
      }

  // ---- O = P*V ----
  f32x4 o[4][2];
#pragma unroll
  for (int i = 0; i < 4; ++i)
#pragma unroll
    for (int j = 0; j < 2; ++j) o[i][j] = (f32x4){0.f, 0.f, 0.f, 0.f};
#pragma unroll
  for (int kt = 0; kt < 2; ++kt) {
    bf16x8 pa[4];
#pragma unroll
    for (int i = 0; i < 4; ++i)
      pa[i] = *(const bf16x8*)(&Psh[wid][i * 16 + fr][kt * 32 + kg * 8]);
#pragma unroll
    for (int i = 0; i < 4; ++i)
#pragma unroll
      for (int j = 0; j < 2; ++j)
        o[i][j] = __builtin_amdgcn_mfma_f32_16x16x32_bf16(pa[i], vf[j][kt], o[i][j], 0, 0, 0);
  }

  // ---- normalize + store ----
#pragma unroll
  for (int i = 0; i < 4; ++i)
#pragma unroll
    for (int r = 0; r < 4; ++r) {
      int n = i * 16 + kg * 4 + r;
      if (n < NW) {
        float inv = 1.f / rsum[i][r];
        bf16* orow = outp + ((size_t)win * NW + n) * CDIM + h * HDIM;
#pragma unroll
        for (int j = 0; j < 2; ++j) orow[j * 16 + fr] = f2b(o[i][j][r] * inv);
      }
    }
}

// ---------------- fused depthwise conv 3x3 + BN + LayerNorm ----------------
__global__ __launch_bounds__(384) void k_convln(const float* __restrict__ x1,
                                                const float* __restrict__ cw,
                                                const float* __restrict__ bng,
                                                const float* __restrict__ bnb,
                                                const float* __restrict__ bnm,
                                                const float* __restrict__ bnv,
                                                const float* __restrict__ lng,
                                                const float* __restrict__ lnb,
                                                float* __restrict__ x2,
                                                bf16* __restrict__ xn2) {
  __shared__ float wT[9][CDIM];          // transposed conv weights: wT[tap][c]
  __shared__ float ls1[4][96], ls2[4][96];
  const int tid = threadIdx.x;
#pragma unroll
  for (int i = 0; i < 9; ++i) {
    int fidx = i * 384 + tid;
    wT[fidx % 9][fidx / 9] = cw[fidx];
  }
  __syncthreads();
  const int ri = tid / 96, j = tid - ri * 96;   // row-in-block, channel quad
  const int rg = blockIdx.x * 4 + ri;
  const int b = rg / LROW, l = rg - b * LROW;
  const int h = l / 28, w = l - h * 28;
  const int c0 = j * 4;
  f32x4 acc = {0.f, 0.f, 0.f, 0.f};
#pragma unroll
  for (int dh = -1; dh <= 1; ++dh) {
    int hh = h + dh;
    if (hh < 0 || hh >= 28) continue;
#pragma unroll
    for (int dw = -1; dw <= 1; ++dw) {
      int ww = w + dw;
      if (ww < 0 || ww >= 28) continue;
      f32x4 xi = *(const f32x4*)(x1 + ((size_t)b * LROW + hh * 28 + ww) * CDIM + c0);
      const float* wt = &wT[(dh + 1) * 3 + (dw + 1)][c0];
      acc[0] += xi[0] * wt[0];
      acc[1] += xi[1] * wt[1];
      acc[2] += xi[2] * wt[2];
      acc[3] += xi[3] * wt[3];
    }
  }
  f32x4 m4 = *(const f32x4*)(bnm + c0), v4 = *(const f32x4*)(bnv + c0);
  f32x4 g4 = *(const f32x4*)(bng + c0), b4 = *(const f32x4*)(bnb + c0);
  f32x4 y;
#pragma unroll
  for (int e = 0; e < 4; ++e)
    y[e] = (acc[e] - m4[e]) * rsqrtf(v4[e] + 1e-5f) * g4[e] + b4[e];
  *(f32x4*)(x2 + (size_t)rg * CDIM + c0) = y;
  ls1[ri][j] = y[0] + y[1] + y[2] + y[3];
  ls2[ri][j] = y[0] * y[0] + y[1] * y[1] + y[2] * y[2] + y[3] * y[3];
  __syncthreads();
  if (j < 32) {
    ls1[ri][j] += ls1[ri][j + 32] + ls1[ri][j + 64];
    ls2[ri][j] += ls2[ri][j + 32] + ls2[ri][j + 64];
  }
  __syncthreads();
  for (int s = 16; s > 0; s >>= 1) {
    if (j < s) { ls1[ri][j] += ls1[ri][j + s]; ls2[ri][j] += ls2[ri][j + s]; }
    __syncthreads();
  }
  const float mean = ls1[ri][0] * (1.f / CDIM);
  const float var = ls2[ri][0] * (1.f / CDIM) - mean * mean;
  const float inv = rsqrtf(var + 1e-5f);
  f32x4 lg = *(const f32x4*)(lng + c0), lb = *(const f32x4*)(lnb + c0);
  short4v ov;
#pragma unroll
  for (int e = 0; e < 4; ++e)
    ov[e] = (short)fbits((y[e] - mean) * inv * lg[e] + lb[e]);
  *(short4v*)((unsigned short*)xn2 + (size_t)rg * CDIM + c0) = ov;
}

extern "C" void kernel_launch(void* const* d_in, const int* in_sizes, int n_in,
                              void* d_out, int out_size, void* d_ws, size_t ws_size,
                              hipStream_t stream) {
  float* out = (float*)d_out;
  static const int EXP[20] = {19267584, 384, 384, 442368, 1152, 588, 2401, 147456, 384, 3456,
                              384, 384, 384, 384, 384, 384, 589824, 1536, 589824, 384};
  const void* p[20];
  bool ok = (n_in == 20);
  int badslot = 30;
  if (ok) {
    bool used[20] = {false};
    for (int i = 0; i < 20 && ok; ++i) {
      int occ = 0;
      for (int j = 0; j < i; ++j) if (EXP[j] == EXP[i]) ++occ;
      int found = -1, seen = 0;
      for (int j = 0; j < 20; ++j) {
        if (in_sizes[j] == EXP[i]) {
          if (seen == occ) { found = j; break; }
          ++seen;
        }
      }
      if (found < 0 || used[found]) { ok = false; badslot = i; break; }
      used[found] = true;
      p[i] = d_in[found];
    }
  }
  const int NOUT = NROWS * CDIM;
  if (!ok) {
    k_fill<<<(NOUT + 255) / 256, 256, 0, stream>>>(out, NOUT, -(2.0f + 0.05f * badslot));
    return;
  }
  const size_t RB = (size_t)NROWS * CDIM;  // 19,267,584 elems
  if (ws_size < RB * 8 + 1024) {
    k_fill<<<(NOUT + 255) / 256, 256, 0, stream>>>(out, NOUT, -5.0f);
    return;
  }
  // ---- workspace plan (peak 8*RB bytes = 154.1 MB, verified) ----
  char* base = (char*)d_ws;
  bf16* xn1 = (bf16*)base;
  bf16* qkvb = (bf16*)(base + RB * 2);
  bf16* attnb = (bf16*)base;
  float* x1 = (float*)(base + RB * 2);
  bf16* wfc1 = (bf16*)(base + RB * 6);
  bf16* wfc2 = (bf16*)(base + RB * 6 + 1179648);
  bf16* xn2 = (bf16*)base;
  bf16* hbuf = (bf16*)(base + RB * 2);
  bf16* wqkv = (bf16*)d_out;                        // d_out scratch, dead before k_convln
  bf16* wproj = (bf16*)d_out + 442368;
  float* biasT = (float*)((char*)d_out + 1179648);  // 196,608 B after the weight scratch

  const float* xin = (const float*)p[0];
  const int noff = 49;

  k_f2b<<<(442368 + 255) / 256, 256, 0, stream>>>((const float*)p[3], wqkv, 442368);
  k_f2b<<<(147456 + 255) / 256, 256, 0, stream>>>((const float*)p[7], wproj, 147456);
  k_biast<<<(NHEADS * 64 * 64 + 255) / 256, 256, 0, stream>>>(
      (const float*)p[5], (const int*)p[6], noff, biasT);

  k_ln_win<<<NROWS, 256, 0, stream>>>(xin, (const float*)p[1], (const float*)p[2], xn1);
  {
    dim3 g(NROWS / 128, QKVD / 128);
    k_gqkv<<<g, 256, 0, stream>>>(xn1, wqkv, (const float*)p[4], qkvb);
  }
  k_attn2<<<(1024 * NHEADS) / 4, 256, 0, stream>>>(qkvb, biasT, attnb);
  k_f2b<<<(589824 + 255) / 256, 256, 0, stream>>>((const float*)p[16], wfc1, 589824);
  k_f2b<<<(589824 + 255) / 256, 256, 0, stream>>>((const float*)p[18], wfc2, 589824);
  {
    dim3 g(NROWS / 128, CDIM / 128);
    k_gproj<<<g, 256, 0, stream>>>(attnb, wproj, (const float*)p[8], xin, x1);
  }
  // fused conv+BN+LN: writes x2 -> d_out (residual carrier) and xn2 -> ws base
  k_convln<<<NROWS / 4, 384, 0, stream>>>(
      x1, (const float*)p[9], (const float*)p[10], (const float*)p[11],
      (const float*)p[12], (const float*)p[13], (const float*)p[14],
      (const float*)p[15], out, xn2);
  {
    dim3 g1(MHALF / 128, MLPH / 128), g2(MHALF / 128, CDIM / 64);
    k_gfc1<<<g1, 256, 0, stream>>>(xn2, wfc1, (const float*)p[17], hbuf);
    k_gfc2<<<g2, 256, 0, stream>>>(hbuf, wfc2, (const float*)p[19], out);
    k_gfc1<<<g1, 256, 0, stream>>>(xn2 + (size_t)MHALF * CDIM, wfc1, (const float*)p[17], hbuf);
    k_gfc2<<<g2, 256, 0, stream>>>(hbuf, wfc2, (const float*)p[19], out + (size_t)MHALF * CDIM);
  }
}

// Round 14
// 691.584 us; speedup vs baseline: 1.0680x; 1.0680x over previous
//
#include <hip/hip_runtime.h>
#include <hip/hip_bf16.h>
#include <math.h>

#define CDIM 384
#define NW 49
#define NHEADS 12
#define HDIM 32
#define LROW 784
#define NROWS 50176        // B*L
#define MLPH 1536
#define QKVD 1152
#define MHALF 25088        // NROWS/2, for MLP half-passes

typedef __hip_bfloat16 bf16;
typedef __attribute__((ext_vector_type(8))) short bf16x8;   // 8 bf16 = 4 VGPR
typedef __attribute__((ext_vector_type(4))) short short4v;  // 4 bf16 = 8B
typedef __attribute__((ext_vector_type(4))) float f32x4;

__device__ __forceinline__ float b2f(bf16 v) { return __bfloat162float(v); }
__device__ __forceinline__ bf16 f2b(float v) { return __float2bfloat16(v); }
__device__ __forceinline__ unsigned short fbits(float v) {
  bf16 t = f2b(v);
  return *(unsigned short*)&t;
}

// ---------------- sentinel fill (fp32) ----------------
__global__ __launch_bounds__(256) void k_fill(float* out, int n, float val) {
  int i = blockIdx.x * 256 + threadIdx.x;
  if (i < n) out[i] = val;
}

// ---------------- fp32 -> bf16 weight convert ----------------
__global__ __launch_bounds__(256) void k_f2b(const float* __restrict__ in,
                                             bf16* __restrict__ out, int n) {
  int i = blockIdx.x * 256 + threadIdx.x;
  if (i < n) out[i] = f2b(in[i]);
}

// ---------------- precompute dense attn bias table ----------------
__global__ __launch_bounds__(256) void k_biast(const float* __restrict__ attn_bias,
                                               const int* __restrict__ bias_idxs,
                                               int noff, float* __restrict__ biasT) {
  int t = blockIdx.x * 256 + threadIdx.x;
  if (t >= NHEADS * 64 * 64) return;
  int j = t & 3, fr = (t >> 2) & 15, n = (t >> 6) & 63, h = t >> 12;
  int m = j * 16 + fr;
  float v = -1e30f;
  if (n < NW && m < NW) v = attn_bias[h * noff + bias_idxs[n * NW + m]];
  biasT[t] = v;
}

// ---------------- LayerNorm -> bf16, scattered to window-row order ----------------
__global__ __launch_bounds__(256) void k_ln_win(const float* __restrict__ in,
                                                const float* __restrict__ g,
                                                const float* __restrict__ b,
                                                bf16* __restrict__ outp) {
  __shared__ float s1[256], s2[256];
  const int tid = threadIdx.x;
  const int rg = blockIdx.x;
  const float* row = in + (size_t)rg * CDIM;
  float a = row[tid];
  float c2 = (tid < CDIM - 256) ? row[tid + 256] : 0.f;
  s1[tid] = a + c2;
  s2[tid] = a * a + c2 * c2;
  __syncthreads();
  for (int s = 128; s > 0; s >>= 1) {
    if (tid < s) { s1[tid] += s1[tid + s]; s2[tid] += s2[tid + s]; }
    __syncthreads();
  }
  const float mean = s1[0] * (1.f / CDIM);
  const float var = s2[0] * (1.f / CDIM) - mean * mean;
  const float inv = rsqrtf(var + 1e-5f);
  int bb = rg / LROW, l = rg - bb * LROW;
  int hs = l / 28, ws = l - hs * 28;
  int wi = hs / 7, r7 = hs - wi * 7, wj = ws / 7, s7 = ws - wj * 7;
  int wrow = (bb * 16 + wi * 4 + wj) * NW + r7 * 7 + s7;
  bf16* orow = outp + (size_t)wrow * CDIM;
  orow[tid] = f2b((row[tid] - mean) * inv * g[tid] + b[tid]);
  if (tid < CDIM - 256)
    orow[tid + 256] = f2b((row[tid + 256] - mean) * inv * g[tid + 256] + b[tid + 256]);
}

// ---------------- MFMA GEMM core v2: C[128x128] += A[128xK] * W[128xK]^T ----------------
// BK=64, global_load_lds width-16 staging, both-sides XOR swizzle (guideline 21).
template<int K>
__device__ __forceinline__ void gemm_tile(const bf16* __restrict__ A,
                                          const bf16* __restrict__ W,
                                          int arow0, int brow0, f32x4 acc[4][4]) {
  __shared__ __align__(16) unsigned short As[128 * 64];
  __shared__ __align__(16) unsigned short Bs[128 * 64];
  const int tid = threadIdx.x;
  const int lane = tid & 63;
  const int wid = tid >> 6;
  const int wr = wid >> 1, wc = wid & 1;       // wave position in 2x2
  const int fr = lane & 15, kg = lane >> 4;    // fragment row, k-group
  const int srow = wid * 32 + (lane >> 3);
  const int scol = (((lane & 7) ^ ((lane >> 3) & 7)) * 8);  // swizzled source col (elems)
  for (int kt = 0; kt < K; kt += 64) {
    if (kt) __syncthreads();   // prior iter's LDS reads done before overwrite
#pragma unroll
    for (int i = 0; i < 4; ++i) {
      __builtin_amdgcn_global_load_lds(
          (const __attribute__((address_space(1))) void*)(A + (size_t)(arow0 + srow + i * 8) * K + kt + scol),
          (__attribute__((address_space(3))) void*)(&As[(wid * 32 + i * 8) * 64]), 16, 0, 0);
      __builtin_amdgcn_global_load_lds(
          (const __attribute__((address_space(1))) void*)(W + (size_t)(brow0 + srow + i * 8) * K + kt + scol),
          (__attribute__((address_space(3))) void*)(&Bs[(wid * 32 + i * 8) * 64]), 16, 0, 0);
    }
    __syncthreads();           // drains vmcnt(0): tiles resident
#pragma unroll
    for (int kk = 0; kk < 2; ++kk) {
      const int slot = ((kk * 4 + kg) ^ (fr & 7)) * 8;
      bf16x8 af[4], bv[4];
#pragma unroll
      for (int i = 0; i < 4; ++i) {
        af[i] = *(const bf16x8*)(&As[(wr * 64 + i * 16 + fr) * 64 + slot]);
        bv[i] = *(const bf16x8*)(&Bs[(wc * 64 + i * 16 + fr) * 64 + slot]);
      }
#pragma unroll
      for (int i = 0; i < 4; ++i)
#pragma unroll
        for (int j = 0; j < 4; ++j)
          acc[i][j] = __builtin_amdgcn_mfma_f32_16x16x32_bf16(af[i], bv[j], acc[i][j], 0, 0, 0);
    }
  }
}

// ---------------- MFMA GEMM core v2-narrow: C[128x64] += A[128xK] * W[64xK]^T ----------------
template<int K>
__device__ __forceinline__ void gemm_tile64(const bf16* __restrict__ A,
                                            const bf16* __restrict__ W,
                                            int arow0, int brow0, f32x4 acc[4][2]) {
  __shared__ __align__(16) unsigned short As[128 * 64];
  __shared__ __align__(16) unsigned short Bs[64 * 64];
  const int tid = threadIdx.x;
  const int lane = tid & 63;
  const int wid = tid >> 6;
  const int wr = wid >> 1, wc = wid & 1;       // wave position in 2x2
  const int fr = lane & 15, kg = lane >> 4;
  const int srowA = wid * 32 + (lane >> 3);    // + i*8, i=0..3
  const int srowB = wid * 16 + (lane >> 3);    // + i*8, i=0..1
  const int scol = (((lane & 7) ^ ((lane >> 3) & 7)) * 8);
  for (int kt = 0; kt < K; kt += 64) {
    if (kt) __syncthreads();
#pragma unroll
    for (int i = 0; i < 4; ++i)
      __builtin_amdgcn_global_load_lds(
          (const __attribute__((address_space(1))) void*)(A + (size_t)(arow0 + srowA + i * 8) * K + kt + scol),
          (__attribute__((address_space(3))) void*)(&As[(wid * 32 + i * 8) * 64]), 16, 0, 0);
#pragma unroll
    for (int i = 0; i < 2; ++i)
      __builtin_amdgcn_global_load_lds(
          (const __attribute__((address_space(1))) void*)(W + (size_t)(brow0 + srowB + i * 8) * K + kt + scol),
          (__attribute__((address_space(3))) void*)(&Bs[(wid * 16 + i * 8) * 64]), 16, 0, 0);
    __syncthreads();
#pragma unroll
    for (int kk = 0; kk < 2; ++kk) {
      const int slot = ((kk * 4 + kg) ^ (fr & 7)) * 8;
      bf16x8 af[4], bv[2];
#pragma unroll
      for (int i = 0; i < 4; ++i)
        af[i] = *(const bf16x8*)(&As[(wr * 64 + i * 16 + fr) * 64 + slot]);
#pragma unroll
      for (int j = 0; j < 2; ++j)
        bv[j] = *(const bf16x8*)(&Bs[(wc * 32 + j * 16 + fr) * 64 + slot]);
#pragma unroll
      for (int i = 0; i < 4; ++i)
#pragma unroll
        for (int j = 0; j < 2; ++j)
          acc[i][j] = __builtin_amdgcn_mfma_f32_16x16x32_bf16(af[i], bv[j], acc[i][j], 0, 0, 0);
    }
  }
}

// XCD-chunked swizzle (T1): consecutive blocks WITHIN an XCD share the A-row-panel.
// Requires nwg % 8 == 0 (all our GEMM grids: 3528/1176/2352/1176). Bijective.
__device__ __forceinline__ int xcd_swz(int l, int nwg) {
  return (l & 7) * (nwg >> 3) + (l >> 3);
}

#define GEMM_PROLOGUE(KK, NCOL)                                             \
  f32x4 acc[4][4];                                                          \
  for (int i = 0; i < 4; ++i)                                               \
    for (int j = 0; j < 4; ++j) acc[i][j] = (f32x4){0.f, 0.f, 0.f, 0.f};    \
  const int swz = xcd_swz(blockIdx.x, gridDim.x);                           \
  const int arow0 = (swz / (NCOL)) * 128, bcol0 = (swz % (NCOL)) * 128;     \
  gemm_tile<KK>(A, W, arow0, bcol0, acc);                                   \
  const int tid = threadIdx.x, lane = tid & 63, wid = tid >> 6;             \
  const int wr = wid >> 1, wc = wid & 1, fr = lane & 15, rq = lane >> 4;

// ---------------- QKV GEMM: out bf16 [wrow, 1152] ----------------
__global__ __launch_bounds__(256) void k_gqkv(const bf16* __restrict__ A,
                                              const bf16* __restrict__ W,
                                              const float* __restrict__ bias,
                                              bf16* __restrict__ out) {
  GEMM_PROLOGUE(CDIM, QKVD / 128)
#pragma unroll
  for (int i = 0; i < 4; ++i)
#pragma unroll
    for (int r = 0; r < 4; ++r) {
      int m = arow0 + wr * 64 + i * 16 + rq * 4 + r;
#pragma unroll
      for (int j = 0; j < 4; ++j) {
        int n = bcol0 + wc * 64 + j * 16 + fr;
        out[(size_t)m * QKVD + n] = f2b(acc[i][j][r] + bias[n]);
      }
    }
}

// ---------------- proj GEMM + bias + residual, scatter window->spatial ----------------
__global__ __launch_bounds__(256) void k_gproj(const bf16* __restrict__ A,
                                               const bf16* __restrict__ W,
                                               const float* __restrict__ bias,
                                               const float* __restrict__ xin,
                                               float* __restrict__ x1) {
  GEMM_PROLOGUE(CDIM, CDIM / 128)
#pragma unroll
  for (int i = 0; i < 4; ++i)
#pragma unroll
    for (int r = 0; r < 4; ++r) {
      int m = arow0 + wr * 64 + i * 16 + rq * 4 + r;   // window row
      int win = m / NW, nn = m - win * NW;
      int bb = win >> 4, wrem = win & 15, wi = wrem >> 2, wj = wrem & 3;
      int r7 = nn / 7, s7 = nn - r7 * 7;
      int l = (wi * 7 + r7) * 28 + wj * 7 + s7;
      size_t srow = (size_t)(bb * LROW + l) * CDIM;
#pragma unroll
      for (int j = 0; j < 4; ++j) {
        int n = bcol0 + wc * 64 + j * 16 + fr;
        x1[srow + n] = xin[srow + n] + acc[i][j][r] + bias[n];
      }
    }
}

// ---------------- FC1 GEMM + GELU: out bf16 [m,1536] ----------------
__global__ __launch_bounds__(256) void k_gfc1(const bf16* __restrict__ A,
                                              const bf16* __restrict__ W,
                                              const float* __restrict__ bias,
                                              bf16* __restrict__ out) {
  GEMM_PROLOGUE(CDIM, MLPH / 128)
#pragma unroll
  for (int i = 0; i < 4; ++i)
#pragma unroll
    for (int r = 0; r < 4; ++r) {
      int m = arow0 + wr * 64 + i * 16 + rq * 4 + r;
#pragma unroll
      for (int j = 0; j < 4; ++j) {
        int n = bcol0 + wc * 64 + j * 16 + fr;
        float v = acc[i][j][r] + bias[n];
        out[(size_t)m * MLPH + n] = f2b(0.5f * v * (1.f + erff(v * 0.70710678118654752f)));
      }
    }
}

// ---------------- FC2 GEMM + bias + residual, BN=64 tile, in-place on xout ----------------
__global__ __launch_bounds__(256) void k_gfc2(const bf16* __restrict__ A,
                                              const bf16* __restrict__ W,
                                              const float* __restrict__ bias,
                                              float* __restrict__ xout) {
  f32x4 acc[4][2];
  for (int i = 0; i < 4; ++i)
    for (int j = 0; j < 2; ++j) acc[i][j] = (f32x4){0.f, 0.f, 0.f, 0.f};
  const int swz = xcd_swz(blockIdx.x, gridDim.x);
  const int arow0 = (swz / 6) * 128, bcol0 = (swz % 6) * 64;
  gemm_tile64<MLPH>(A, W, arow0, bcol0, acc);
  const int tid = threadIdx.x, lane = tid & 63, wid = tid >> 6;
  const int wr = wid >> 1, wc = wid & 1, fr = lane & 15, rq = lane >> 4;
#pragma unroll
  for (int i = 0; i < 4; ++i)
#pragma unroll
    for (int r = 0; r < 4; ++r) {
      int m = arow0 + wr * 64 + i * 16 + rq * 4 + r;
#pragma unroll
      for (int j = 0; j < 2; ++j) {
        int n = bcol0 + wc * 32 + j * 16 + fr;
        size_t dst = (size_t)m * CDIM + n;
        xout[dst] = xout[dst] + acc[i][j][r] + bias[n];
      }
    }
}

// ---------------- attention v3: one WAVE per (win, head), dense bias table ----------------
__global__ __launch_bounds__(256) void k_attn2(const bf16* __restrict__ qkv,
                                               const float* __restrict__ biasT,
                                               bf16* __restrict__ outp) {
  __shared__ __align__(16) unsigned short Psh[4][64][72];
  const int tid = threadIdx.x;
  const int wid = tid >> 6, lane = tid & 63;
  const int fr = lane & 15, kg = lane >> 4;
  const int gid = blockIdx.x * 4 + wid;          // win*NHEADS + h
  const int win = gid / NHEADS, h = gid - win * NHEADS;
  const bf16* base = qkv + (size_t)win * NW * QKVD + h * 96;  // q|k|v 32-col slices

  // ---- QK^T ----
  const bf16x8 zero8 = {0, 0, 0, 0, 0, 0, 0, 0};
  bf16x8 qf[4], kf[4];
#pragma unroll
  for (int i = 0; i < 4; ++i) {
    int rr = i * 16 + fr;
    qf[i] = (rr < NW) ? *(const bf16x8*)(base + (size_t)rr * QKVD + kg * 8) : zero8;
    kf[i] = (rr < NW) ? *(const bf16x8*)(base + (size_t)rr * QKVD + 32 + kg * 8) : zero8;
  }
  f32x4 s[4][4];
#pragma unroll
  for (int i = 0; i < 4; ++i)
#pragma unroll
    for (int j = 0; j < 4; ++j)
      s[i][j] = (f32x4){0.f, 0.f, 0.f, 0.f};
#pragma unroll
  for (int i = 0; i < 4; ++i)
#pragma unroll
    for (int j = 0; j < 4; ++j)
      s[i][j] = __builtin_amdgcn_mfma_f32_16x16x32_bf16(qf[i], kf[j], s[i][j], 0, 0, 0);

  // ---- bias (one f32x4 per row from dense table) + softmax ----
  const float scale = 0.17677669529663687f;
  const float* btab = biasT + (((size_t)h * 64) * 16 + fr) * 4;
  float rsum[4][4];
#pragma unroll
  for (int i = 0; i < 4; ++i)
#pragma unroll
    for (int r = 0; r < 4; ++r) {
      int n = i * 16 + kg * 4 + r;
      f32x4 b4 = *(const f32x4*)(btab + (size_t)n * 64);
      float mx = -1e30f;
#pragma unroll
      for (int j = 0; j < 4; ++j) {
        float v = s[i][j][r] * scale + b4[j];
        s[i][j][r] = v;
        mx = fmaxf(mx, v);
      }
#pragma unroll
      for (int msk = 1; msk < 16; msk <<= 1) mx = fmaxf(mx, __shfl_xor(mx, msk));
      float sum = 0.f;
#pragma unroll
      for (int j = 0; j < 4; ++j) {
        float e = __expf(s[i][j][r] - mx);
        s[i][j][r] = e;
        sum += e;
      }
#pragma unroll
      for (int msk = 1; msk < 16; msk <<= 1) sum += __shfl_xor(sum, msk);
      rsum[i][r] = sum;
    }

  // ---- P -> LDS (bf16) ----
#pragma unroll
  for (int i = 0; i < 4; ++i)
#pragma unroll
    for (int r = 0; r < 4; ++r) {
      int n = i * 16 + kg * 4 + r;
#pragma unroll
      for (int j = 0; j < 4; ++j) {
        Psh[wid][n][j * 16 + fr] = fbits(s[i][j][r]);
      }
    }
  __syncthreads();

  // ---- V^T fragments ----
  bf16x8 vf[2][2];  // [d-tile j][k-tile kt]
#pragma unroll
  for (int j = 0; j < 2; ++j)
#pragma unroll
    for (int kt = 0; kt < 2; ++kt)
#pragma unroll
      for (int e = 0; e < 8; ++e) {
        int m = kt * 32 + kg * 8 + e;
        bf16 val = (m < NW) ? base[(size_t)m * QKVD + 64 + j * 16 + fr] : f2b(0.f);
        vf[j][kt][e] = *(short*)&val;
      }

  // ---- O = P*V ----
  f32x4 o[4][2];
#pragma unroll
  for (int i = 0; i < 4; ++i)
#pragma unroll
    for (int j = 0; j < 2; ++j) o[i][j] = (f32x4){0.f, 0.f, 0.f, 0.f};
#pragma unroll
  for (int kt = 0; kt < 2; ++kt) {
    bf16x8 pa[4];
#pragma unroll
    for (int i = 0; i < 4; ++i)
      pa[i] = *(const bf16x8*)(&Psh[wid][i * 16 + fr][kt * 32 + kg * 8]);
#pragma unroll
    for (int i = 0; i < 4; ++i)
#pragma unroll
      for (int j = 0; j < 2; ++j)
        o[i][j] = __builtin_amdgcn_mfma_f32_16x16x32_bf16(pa[i], vf[j][kt], o[i][j], 0, 0, 0);
  }

  // ---- normalize + store ----
#pragma unroll
  for (int i = 0; i < 4; ++i)
#pragma unroll
    for (int r = 0; r < 4; ++r) {
      int n = i * 16 + kg * 4 + r;
      if (n < NW) {
        float inv = 1.f / rsum[i][r];
        bf16* orow = outp + ((size_t)win * NW + n) * CDIM + h * HDIM;
#pragma unroll
        for (int j = 0; j < 2; ++j) orow[j * 16 + fr] = f2b(o[i][j][r] * inv);
      }
    }
}

// ---------------- fused depthwise conv 3x3 + BN + LayerNorm ----------------
__global__ __launch_bounds__(384) void k_convln(const float* __restrict__ x1,
                                                const float* __restrict__ cw,
                                                const float* __restrict__ bng,
                                                const float* __restrict__ bnb,
                                                const float* __restrict__ bnm,
                                                const float* __restrict__ bnv,
                                                const float* __restrict__ lng,
                                                const float* __restrict__ lnb,
                                                float* __restrict__ x2,
                                                bf16* __restrict__ xn2) {
  __shared__ float wT[9][CDIM];          // transposed conv weights: wT[tap][c]
  __shared__ float ls1[4][96], ls2[4][96];
  const int tid = threadIdx.x;
#pragma unroll
  for (int i = 0; i < 9; ++i) {
    int fidx = i * 384 + tid;
    wT[fidx % 9][fidx / 9] = cw[fidx];
  }
  __syncthreads();
  const int ri = tid / 96, j = tid - ri * 96;   // row-in-block, channel quad
  const int rg = blockIdx.x * 4 + ri;
  const int b = rg / LROW, l = rg - b * LROW;
  const int h = l / 28, w = l - h * 28;
  const int c0 = j * 4;
  f32x4 acc = {0.f, 0.f, 0.f, 0.f};
#pragma unroll
  for (int dh = -1; dh <= 1; ++dh) {
    int hh = h + dh;
    if (hh < 0 || hh >= 28) continue;
#pragma unroll
    for (int dw = -1; dw <= 1; ++dw) {
      int ww = w + dw;
      if (ww < 0 || ww >= 28) continue;
      f32x4 xi = *(const f32x4*)(x1 + ((size_t)b * LROW + hh * 28 + ww) * CDIM + c0);
      const float* wt = &wT[(dh + 1) * 3 + (dw + 1)][c0];
      acc[0] += xi[0] * wt[0];
      acc[1] += xi[1] * wt[1];
      acc[2] += xi[2] * wt[2];
      acc[3] += xi[3] * wt[3];
    }
  }
  f32x4 m4 = *(const f32x4*)(bnm + c0), v4 = *(const f32x4*)(bnv + c0);
  f32x4 g4 = *(const f32x4*)(bng + c0), b4 = *(const f32x4*)(bnb + c0);
  f32x4 y;
#pragma unroll
  for (int e = 0; e < 4; ++e)
    y[e] = (acc[e] - m4[e]) * rsqrtf(v4[e] + 1e-5f) * g4[e] + b4[e];
  *(f32x4*)(x2 + (size_t)rg * CDIM + c0) = y;
  ls1[ri][j] = y[0] + y[1] + y[2] + y[3];
  ls2[ri][j] = y[0] * y[0] + y[1] * y[1] + y[2] * y[2] + y[3] * y[3];
  __syncthreads();
  if (j < 32) {
    ls1[ri][j] += ls1[ri][j + 32] + ls1[ri][j + 64];
    ls2[ri][j] += ls2[ri][j + 32] + ls2[ri][j + 64];
  }
  __syncthreads();
  for (int s = 16; s > 0; s >>= 1) {
    if (j < s) { ls1[ri][j] += ls1[ri][j + s]; ls2[ri][j] += ls2[ri][j + s]; }
    __syncthreads();
  }
  const float mean = ls1[ri][0] * (1.f / CDIM);
  const float var = ls2[ri][0] * (1.f / CDIM) - mean * mean;
  const float inv = rsqrtf(var + 1e-5f);
  f32x4 lg = *(const f32x4*)(lng + c0), lb = *(const f32x4*)(lnb + c0);
  short4v ov;
#pragma unroll
  for (int e = 0; e < 4; ++e)
    ov[e] = (short)fbits((y[e] - mean) * inv * lg[e] + lb[e]);
  *(short4v*)((unsigned short*)xn2 + (size_t)rg * CDIM + c0) = ov;
}

extern "C" void kernel_launch(void* const* d_in, const int* in_sizes, int n_in,
                              void* d_out, int out_size, void* d_ws, size_t ws_size,
                              hipStream_t stream) {
  float* out = (float*)d_out;
  static const int EXP[20] = {19267584, 384, 384, 442368, 1152, 588, 2401, 147456, 384, 3456,
                              384, 384, 384, 384, 384, 384, 589824, 1536, 589824, 384};
  const void* p[20];
  bool ok = (n_in == 20);
  int badslot = 30;
  if (ok) {
    bool used[20] = {false};
    for (int i = 0; i < 20 && ok; ++i) {
      int occ = 0;
      for (int j = 0; j < i; ++j) if (EXP[j] == EXP[i]) ++occ;
      int found = -1, seen = 0;
      for (int j = 0; j < 20; ++j) {
        if (in_sizes[j] == EXP[i]) {
          if (seen == occ) { found = j; break; }
          ++seen;
        }
      }
      if (found < 0 || used[found]) { ok = false; badslot = i; break; }
      used[found] = true;
      p[i] = d_in[found];
    }
  }
  const int NOUT = NROWS * CDIM;
  if (!ok) {
    k_fill<<<(NOUT + 255) / 256, 256, 0, stream>>>(out, NOUT, -(2.0f + 0.05f * badslot));
    return;
  }
  const size_t RB = (size_t)NROWS * CDIM;  // 19,267,584 elems
  if (ws_size < RB * 8 + 1024) {
    k_fill<<<(NOUT + 255) / 256, 256, 0, stream>>>(out, NOUT, -5.0f);
    return;
  }
  // ---- workspace plan (peak 8*RB bytes = 154.1 MB, verified) ----
  char* base = (char*)d_ws;
  bf16* xn1 = (bf16*)base;
  bf16* qkvb = (bf16*)(base + RB * 2);
  bf16* attnb = (bf16*)base;
  float* x1 = (float*)(base + RB * 2);
  bf16* wfc1 = (bf16*)(base + RB * 6);
  bf16* wfc2 = (bf16*)(base + RB * 6 + 1179648);
  bf16* xn2 = (bf16*)base;
  bf16* hbuf = (bf16*)(base + RB * 2);
  bf16* wqkv = (bf16*)d_out;                        // d_out scratch, dead before k_convln
  bf16* wproj = (bf16*)d_out + 442368;
  float* biasT = (float*)((char*)d_out + 1179648);  // 196,608 B after the weight scratch

  const float* xin = (const float*)p[0];
  const int noff = 49;

  k_f2b<<<(442368 + 255) / 256, 256, 0, stream>>>((const float*)p[3], wqkv, 442368);
  k_f2b<<<(147456 + 255) / 256, 256, 0, stream>>>((const float*)p[7], wproj, 147456);
  k_biast<<<(NHEADS * 64 * 64 + 255) / 256, 256, 0, stream>>>(
      (const float*)p[5], (const int*)p[6], noff, biasT);

  k_ln_win<<<NROWS, 256, 0, stream>>>(xin, (const float*)p[1], (const float*)p[2], xn1);
  k_gqkv<<<(NROWS / 128) * (QKVD / 128), 256, 0, stream>>>(
      xn1, wqkv, (const float*)p[4], qkvb);
  k_attn2<<<(1024 * NHEADS) / 4, 256, 0, stream>>>(qkvb, biasT, attnb);
  k_f2b<<<(589824 + 255) / 256, 256, 0, stream>>>((const float*)p[16], wfc1, 589824);
  k_f2b<<<(589824 + 255) / 256, 256, 0, stream>>>((const float*)p[18], wfc2, 589824);
  k_gproj<<<(NROWS / 128) * (CDIM / 128), 256, 0, stream>>>(
      attnb, wproj, (const float*)p[8], xin, x1);
  // fused conv+BN+LN: writes x2 -> d_out (residual carrier) and xn2 -> ws base
  k_convln<<<NROWS / 4, 384, 0, stream>>>(
      x1, (const float*)p[9], (const float*)p[10], (const float*)p[11],
      (const float*)p[12], (const float*)p[13], (const float*)p[14],
      (const float*)p[15], out, xn2);
  {
    const int g1 = (MHALF / 128) * (MLPH / 128);   // 2352
    const int g2 = (MHALF / 128) * (CDIM / 64);    // 1176
    k_gfc1<<<g1, 256, 0, stream>>>(xn2, wfc1, (const float*)p[17], hbuf);
    k_gfc2<<<g2, 256, 0, stream>>>(hbuf, wfc2, (const float*)p[19], out);
    k_gfc1<<<g1, 256, 0, stream>>>(xn2 + (size_t)MHALF * CDIM, wfc1, (const float*)p[17], hbuf);
    k_gfc2<<<g2, 256, 0, stream>>>(hbuf, wfc2, (const float*)p[19], out + (size_t)MHALF * CDIM);
  }
}

// Round 15
// 683.393 us; speedup vs baseline: 1.0808x; 1.0120x over previous
//
#include <hip/hip_runtime.h>
#include <hip/hip_bf16.h>
#include <math.h>

#define CDIM 384
#define NW 49
#define NHEADS 12
#define HDIM 32
#define LROW 784
#define NROWS 50176        // B*L
#define MLPH 1536
#define QKVD 1152
#define MHALF 25088        // NROWS/2, for MLP half-passes

typedef __hip_bfloat16 bf16;
typedef __attribute__((ext_vector_type(8))) short bf16x8;   // 8 bf16 = 4 VGPR
typedef __attribute__((ext_vector_type(4))) short short4v;  // 4 bf16 = 8B
typedef __attribute__((ext_vector_type(4))) float f32x4;

__device__ __forceinline__ float b2f(bf16 v) { return __bfloat162float(v); }
__device__ __forceinline__ bf16 f2b(float v) { return __float2bfloat16(v); }
__device__ __forceinline__ unsigned short fbits(float v) {
  bf16 t = f2b(v);
  return *(unsigned short*)&t;
}

// ---------------- sentinel fill (fp32) ----------------
__global__ __launch_bounds__(256) void k_fill(float* out, int n, float val) {
  int i = blockIdx.x * 256 + threadIdx.x;
  if (i < n) out[i] = val;
}

// ---------------- fp32 -> bf16 weight convert ----------------
__global__ __launch_bounds__(256) void k_f2b(const float* __restrict__ in,
                                             bf16* __restrict__ out, int n) {
  int i = blockIdx.x * 256 + threadIdx.x;
  if (i < n) out[i] = f2b(in[i]);
}

// ---------------- precompute dense attn bias table ----------------
__global__ __launch_bounds__(256) void k_biast(const float* __restrict__ attn_bias,
                                               const int* __restrict__ bias_idxs,
                                               int noff, float* __restrict__ biasT) {
  int t = blockIdx.x * 256 + threadIdx.x;
  if (t >= NHEADS * 64 * 64) return;
  int j = t & 3, fr = (t >> 2) & 15, n = (t >> 6) & 63, h = t >> 12;
  int m = j * 16 + fr;
  float v = -1e30f;
  if (n < NW && m < NW) v = attn_bias[h * noff + bias_idxs[n * NW + m]];
  biasT[t] = v;
}

// ---------------- LayerNorm -> bf16, scattered to window-row order ----------------
__global__ __launch_bounds__(256) void k_ln_win(const float* __restrict__ in,
                                                const float* __restrict__ g,
                                                const float* __restrict__ b,
                                                bf16* __restrict__ outp) {
  __shared__ float s1[256], s2[256];
  const int tid = threadIdx.x;
  const int rg = blockIdx.x;
  const float* row = in + (size_t)rg * CDIM;
  float a = row[tid];
  float c2 = (tid < CDIM - 256) ? row[tid + 256] : 0.f;
  s1[tid] = a + c2;
  s2[tid] = a * a + c2 * c2;
  __syncthreads();
  for (int s = 128; s > 0; s >>= 1) {
    if (tid < s) { s1[tid] += s1[tid + s]; s2[tid] += s2[tid + s]; }
    __syncthreads();
  }
  const float mean = s1[0] * (1.f / CDIM);
  const float var = s2[0] * (1.f / CDIM) - mean * mean;
  const float inv = rsqrtf(var + 1e-5f);
  int bb = rg / LROW, l = rg - bb * LROW;
  int hs = l / 28, ws = l - hs * 28;
  int wi = hs / 7, r7 = hs - wi * 7, wj = ws / 7, s7 = ws - wj * 7;
  int wrow = (bb * 16 + wi * 4 + wj) * NW + r7 * 7 + s7;
  bf16* orow = outp + (size_t)wrow * CDIM;
  orow[tid] = f2b((row[tid] - mean) * inv * g[tid] + b[tid]);
  if (tid < CDIM - 256)
    orow[tid + 256] = f2b((row[tid + 256] - mean) * inv * g[tid + 256] + b[tid + 256]);
}

// ---------------- MFMA GEMM core v2: C[128x128] += A[128xK] * W[128xK]^T ----------------
// BK=64, global_load_lds width-16 staging, both-sides XOR swizzle (guideline 21).
template<int K>
__device__ __forceinline__ void gemm_tile(const bf16* __restrict__ A,
                                          const bf16* __restrict__ W,
                                          int arow0, int brow0, f32x4 acc[4][4]) {
  __shared__ __align__(16) unsigned short As[128 * 64];
  __shared__ __align__(16) unsigned short Bs[128 * 64];
  const int tid = threadIdx.x;
  const int lane = tid & 63;
  const int wid = tid >> 6;
  const int wr = wid >> 1, wc = wid & 1;       // wave position in 2x2
  const int fr = lane & 15, kg = lane >> 4;    // fragment row, k-group
  const int srow = wid * 32 + (lane >> 3);
  const int scol = (((lane & 7) ^ ((lane >> 3) & 7)) * 8);  // swizzled source col (elems)
  for (int kt = 0; kt < K; kt += 64) {
    if (kt) __syncthreads();   // prior iter's LDS reads done before overwrite
#pragma unroll
    for (int i = 0; i < 4; ++i) {
      __builtin_amdgcn_global_load_lds(
          (const __attribute__((address_space(1))) void*)(A + (size_t)(arow0 + srow + i * 8) * K + kt + scol),
          (__attribute__((address_space(3))) void*)(&As[(wid * 32 + i * 8) * 64]), 16, 0, 0);
      __builtin_amdgcn_global_load_lds(
          (const __attribute__((address_space(1))) void*)(W + (size_t)(brow0 + srow + i * 8) * K + kt + scol),
          (__attribute__((address_space(3))) void*)(&Bs[(wid * 32 + i * 8) * 64]), 16, 0, 0);
    }
    __syncthreads();           // drains vmcnt(0): tiles resident
#pragma unroll
    for (int kk = 0; kk < 2; ++kk) {
      const int slot = ((kk * 4 + kg) ^ (fr & 7)) * 8;
      bf16x8 af[4], bv[4];
#pragma unroll
      for (int i = 0; i < 4; ++i) {
        af[i] = *(const bf16x8*)(&As[(wr * 64 + i * 16 + fr) * 64 + slot]);
        bv[i] = *(const bf16x8*)(&Bs[(wc * 64 + i * 16 + fr) * 64 + slot]);
      }
#pragma unroll
      for (int i = 0; i < 4; ++i)
#pragma unroll
        for (int j = 0; j < 4; ++j)
          acc[i][j] = __builtin_amdgcn_mfma_f32_16x16x32_bf16(af[i], bv[j], acc[i][j], 0, 0, 0);
    }
  }
}

// ---------------- MFMA GEMM core v2-narrow: C[128x64] += A[128xK] * W[64xK]^T ----------------
template<int K>
__device__ __forceinline__ void gemm_tile64(const bf16* __restrict__ A,
                                            const bf16* __restrict__ W,
                                            int arow0, int brow0, f32x4 acc[4][2]) {
  __shared__ __align__(16) unsigned short As[128 * 64];
  __shared__ __align__(16) unsigned short Bs[64 * 64];
  const int tid = threadIdx.x;
  const int lane = tid & 63;
  const int wid = tid >> 6;
  const int wr = wid >> 1, wc = wid & 1;       // wave position in 2x2
  const int fr = lane & 15, kg = lane >> 4;
  const int srowA = wid * 32 + (lane >> 3);    // + i*8, i=0..3
  const int srowB = wid * 16 + (lane >> 3);    // + i*8, i=0..1
  const int scol = (((lane & 7) ^ ((lane >> 3) & 7)) * 8);
  for (int kt = 0; kt < K; kt += 64) {
    if (kt) __syncthreads();
#pragma unroll
    for (int i = 0; i < 4; ++i)
      __builtin_amdgcn_global_load_lds(
          (const __attribute__((address_space(1))) void*)(A + (size_t)(arow0 + srowA + i * 8) * K + kt + scol),
          (__attribute__((address_space(3))) void*)(&As[(wid * 32 + i * 8) * 64]), 16, 0, 0);
#pragma unroll
    for (int i = 0; i < 2; ++i)
      __builtin_amdgcn_global_load_lds(
          (const __attribute__((address_space(1))) void*)(W + (size_t)(brow0 + srowB + i * 8) * K + kt + scol),
          (__attribute__((address_space(3))) void*)(&Bs[(wid * 16 + i * 8) * 64]), 16, 0, 0);
    __syncthreads();
#pragma unroll
    for (int kk = 0; kk < 2; ++kk) {
      const int slot = ((kk * 4 + kg) ^ (fr & 7)) * 8;
      bf16x8 af[4], bv[2];
#pragma unroll
      for (int i = 0; i < 4; ++i)
        af[i] = *(const bf16x8*)(&As[(wr * 64 + i * 16 + fr) * 64 + slot]);
#pragma unroll
      for (int j = 0; j < 2; ++j)
        bv[j] = *(const bf16x8*)(&Bs[(wc * 32 + j * 16 + fr) * 64 + slot]);
#pragma unroll
      for (int i = 0; i < 4; ++i)
#pragma unroll
        for (int j = 0; j < 2; ++j)
          acc[i][j] = __builtin_amdgcn_mfma_f32_16x16x32_bf16(af[i], bv[j], acc[i][j], 0, 0, 0);
    }
  }
}

// XCD-chunked swizzle (T1): consecutive blocks WITHIN an XCD share the A-row-panel.
// Requires nwg % 8 == 0 (all our GEMM grids: 3528/1176/2352/1176). Bijective.
__device__ __forceinline__ int xcd_swz(int l, int nwg) {
  return (l & 7) * (nwg >> 3) + (l >> 3);
}

#define GEMM_PROLOGUE(KK, NCOL)                                             \
  f32x4 acc[4][4];                                                          \
  for (int i = 0; i < 4; ++i)                                               \
    for (int j = 0; j < 4; ++j) acc[i][j] = (f32x4){0.f, 0.f, 0.f, 0.f};    \
  const int swz = xcd_swz(blockIdx.x, gridDim.x);                           \
  const int arow0 = (swz / (NCOL)) * 128, bcol0 = (swz % (NCOL)) * 128;     \
  gemm_tile<KK>(A, W, arow0, bcol0, acc);                                   \
  const int tid = threadIdx.x, lane = tid & 63, wid = tid >> 6;             \
  const int wr = wid >> 1, wc = wid & 1, fr = lane & 15, rq = lane >> 4;

// ---------------- QKV GEMM: out bf16 [wrow, 1152] ----------------
__global__ __launch_bounds__(256) void k_gqkv(const bf16* __restrict__ A,
                                              const bf16* __restrict__ W,
                                              const float* __restrict__ bias,
                                              bf16* __restrict__ out) {
  GEMM_PROLOGUE(CDIM, QKVD / 128)
#pragma unroll
  for (int i = 0; i < 4; ++i)
#pragma unroll
    for (int r = 0; r < 4; ++r) {
      int m = arow0 + wr * 64 + i * 16 + rq * 4 + r;
#pragma unroll
      for (int j = 0; j < 4; ++j) {
        int n = bcol0 + wc * 64 + j * 16 + fr;
        out[(size_t)m * QKVD + n] = f2b(acc[i][j][r] + bias[n]);
      }
    }
}

// ---------------- proj GEMM + bias + residual, scatter window->spatial ----------------
__global__ __launch_bounds__(256) void k_gproj(const bf16* __restrict__ A,
                                               const bf16* __restrict__ W,
                                               const float* __restrict__ bias,
                                               const float* __restrict__ xin,
                                               float* __restrict__ x1) {
  GEMM_PROLOGUE(CDIM, CDIM / 128)
#pragma unroll
  for (int i = 0; i < 4; ++i)
#pragma unroll
    for (int r = 0; r < 4; ++r) {
      int m = arow0 + wr * 64 + i * 16 + rq * 4 + r;   // window row
      int win = m / NW, nn = m - win * NW;
      int bb = win >> 4, wrem = win & 15, wi = wrem >> 2, wj = wrem & 3;
      int r7 = nn / 7, s7 = nn - r7 * 7;
      int l = (wi * 7 + r7) * 28 + wj * 7 + s7;
      size_t srow = (size_t)(bb * LROW + l) * CDIM;
#pragma unroll
      for (int j = 0; j < 4; ++j) {
        int n = bcol0 + wc * 64 + j * 16 + fr;
        x1[srow + n] = xin[srow + n] + acc[i][j][r] + bias[n];
      }
    }
}

// ---------------- FC1 GEMM + GELU: out bf16 [m,1536] ----------------
__global__ __launch_bounds__(256) void k_gfc1(const bf16* __restrict__ A,
                                              const bf16* __restrict__ W,
                                              const float* __restrict__ bias,
                                              bf16* __restrict__ out) {
  GEMM_PROLOGUE(CDIM, MLPH / 128)
#pragma unroll
  for (int i = 0; i < 4; ++i)
#pragma unroll
    for (int r = 0; r < 4; ++r) {
      int m = arow0 + wr * 64 + i * 16 + rq * 4 + r;
#pragma unroll
      for (int j = 0; j < 4; ++j) {
        int n = bcol0 + wc * 64 + j * 16 + fr;
        float v = acc[i][j][r] + bias[n];
        out[(size_t)m * MLPH + n] = f2b(0.5f * v * (1.f + erff(v * 0.70710678118654752f)));
      }
    }
}

// ---------------- FC2 GEMM + bias + residual, BN=64 tile, in-place on xout ----------------
__global__ __launch_bounds__(256) void k_gfc2(const bf16* __restrict__ A,
                                              const bf16* __restrict__ W,
                                              const float* __restrict__ bias,
                                              float* __restrict__ xout) {
  f32x4 acc[4][2];
  for (int i = 0; i < 4; ++i)
    for (int j = 0; j < 2; ++j) acc[i][j] = (f32x4){0.f, 0.f, 0.f, 0.f};
  const int swz = xcd_swz(blockIdx.x, gridDim.x);
  const int arow0 = (swz / 6) * 128, bcol0 = (swz % 6) * 64;
  gemm_tile64<MLPH>(A, W, arow0, bcol0, acc);
  const int tid = threadIdx.x, lane = tid & 63, wid = tid >> 6;
  const int wr = wid >> 1, wc = wid & 1, fr = lane & 15, rq = lane >> 4;
#pragma unroll
  for (int i = 0; i < 4; ++i)
#pragma unroll
    for (int r = 0; r < 4; ++r) {
      int m = arow0 + wr * 64 + i * 16 + rq * 4 + r;
#pragma unroll
      for (int j = 0; j < 2; ++j) {
        int n = bcol0 + wc * 32 + j * 16 + fr;
        size_t dst = (size_t)m * CDIM + n;
        xout[dst] = xout[dst] + acc[i][j][r] + bias[n];
      }
    }
}

// ---------------- attention v3: one WAVE per (win, head), dense bias table ----------------
__global__ __launch_bounds__(256) void k_attn2(const bf16* __restrict__ qkv,
                                               const float* __restrict__ biasT,
                                               bf16* __restrict__ outp) {
  __shared__ __align__(16) unsigned short Psh[4][64][72];
  const int tid = threadIdx.x;
  const int wid = tid >> 6, lane = tid & 63;
  const int fr = lane & 15, kg = lane >> 4;
  const int gid = blockIdx.x * 4 + wid;          // win*NHEADS + h
  const int win = gid / NHEADS, h = gid - win * NHEADS;
  const bf16* base = qkv + (size_t)win * NW * QKVD + h * 96;  // q|k|v 32-col slices

  // ---- QK^T ----
  const bf16x8 zero8 = {0, 0, 0, 0, 0, 0, 0, 0};
  bf16x8 qf[4], kf[4];
#pragma unroll
  for (int i = 0; i < 4; ++i) {
    int rr = i * 16 + fr;
    qf[i] = (rr < NW) ? *(const bf16x8*)(base + (size_t)rr * QKVD + kg * 8) : zero8;
    kf[i] = (rr < NW) ? *(const bf16x8*)(base + (size_t)rr * QKVD + 32 + kg * 8) : zero8;
  }
  f32x4 s[4][4];
#pragma unroll
  for (int i = 0; i < 4; ++i)
#pragma unroll
    for (int j = 0; j < 4; ++j)
      s[i][j] = (f32x4){0.f, 0.f, 0.f, 0.f};
#pragma unroll
  for (int i = 0; i < 4; ++i)
#pragma unroll
    for (int j = 0; j < 4; ++j)
      s[i][j] = __builtin_amdgcn_mfma_f32_16x16x32_bf16(qf[i], kf[j], s[i][j], 0, 0, 0);

  // ---- bias (one f32x4 per row from dense table) + softmax ----
  const float scale = 0.17677669529663687f;
  const float* btab = biasT + (((size_t)h * 64) * 16 + fr) * 4;
  float rsum[4][4];
#pragma unroll
  for (int i = 0; i < 4; ++i)
#pragma unroll
    for (int r = 0; r < 4; ++r) {
      int n = i * 16 + kg * 4 + r;
      f32x4 b4 = *(const f32x4*)(btab + (size_t)n * 64);
      float mx = -1e30f;
#pragma unroll
      for (int j = 0; j < 4; ++j) {
        float v = s[i][j][r] * scale + b4[j];
        s[i][j][r] = v;
        mx = fmaxf(mx, v);
      }
#pragma unroll
      for (int msk = 1; msk < 16; msk <<= 1) mx = fmaxf(mx, __shfl_xor(mx, msk));
      float sum = 0.f;
#pragma unroll
      for (int j = 0; j < 4; ++j) {
        float e = __expf(s[i][j][r] - mx);
        s[i][j][r] = e;
        sum += e;
      }
#pragma unroll
      for (int msk = 1; msk < 16; msk <<= 1) sum += __shfl_xor(sum, msk);
      rsum[i][r] = sum;
    }

  // ---- P -> LDS (bf16) ----
#pragma unroll
  for (int i = 0; i < 4; ++i)
#pragma unroll
    for (int r = 0; r < 4; ++r) {
      int n = i * 16 + kg * 4 + r;
#pragma unroll
      for (int j = 0; j < 4; ++j) {
        Psh[wid][n][j * 16 + fr] = fbits(s[i][j][r]);
      }
    }
  __syncthreads();

  // ---- V^T fragments ----
  bf16x8 vf[2][2];  // [d-tile j][k-tile kt]
#pragma unroll
  for (int j = 0; j < 2; ++j)
#pragma unroll
    for (int kt = 0; kt < 2; ++kt)
#pragma unroll
      for (int e = 0; e < 8; ++e) {
        int m = kt * 32 + kg * 8 + e;
        bf16 val = (m < NW) ? base[(size_t)m * QKVD + 64 + j * 16 + fr] : f2b(0.f);
        vf[j][kt][e] = *(short*)&val;
      }

  // ---- O = P*V ----
  f32x4 o[4][2];
#pragma unroll
  for (int i = 0; i < 4; ++i)
#pragma unroll
    for (int j = 0; j < 2; ++j) o[i][j] = (f32x4){0.f, 0.f, 0.f, 0.f};
#pragma unroll
  for (int kt = 0; kt < 2; ++kt) {
    bf16x8 pa[4];
#pragma unroll
    for (int i = 0; i < 4; ++i)
      pa[i] = *(const bf16x8*)(&Psh[wid][i * 16 + fr][kt * 32 + kg * 8]);
#pragma unroll
    for (int i = 0; i < 4; ++i)
#pragma unroll
      for (int j = 0; j < 2; ++j)
        o[i][j] = __builtin_amdgcn_mfma_f32_16x16x32_bf16(pa[i], vf[j][kt], o[i][j], 0, 0, 0);
  }

  // ---- normalize + store ----
#pragma unroll
  for (int i = 0; i < 4; ++i)
#pragma unroll
    for (int r = 0; r < 4; ++r) {
      int n = i * 16 + kg * 4 + r;
      if (n < NW) {
        float inv = 1.f / rsum[i][r];
        bf16* orow = outp + ((size_t)win * NW + n) * CDIM + h * HDIM;
#pragma unroll
        for (int j = 0; j < 2; ++j) orow[j * 16 + fr] = f2b(o[i][j][r] * inv);
      }
    }
}

// ---------------- fused depthwise conv 3x3 + BN + LayerNorm (v2: reg weights) ----------------
// Conv weights live in per-thread REGISTERS (9 f32x4 contiguous global loads per thread,
// L1-resident 13.8 KB) — eliminates the 8-way-conflicted wT LDS staging/reads (10.8M
// conflict cycles in v1). cw layout [c*9+tap]: thread's channels c0..c0+3 = 36 contiguous
// floats at cw[c0*9], 16B-aligned (c0*9*4 = 144*j). Statically transposed in registers.
__global__ __launch_bounds__(384) void k_convln(const float* __restrict__ x1,
                                                const float* __restrict__ cw,
                                                const float* __restrict__ bng,
                                                const float* __restrict__ bnb,
                                                const float* __restrict__ bnm,
                                                const float* __restrict__ bnv,
                                                const float* __restrict__ lng,
                                                const float* __restrict__ lnb,
                                                float* __restrict__ x2,
                                                bf16* __restrict__ xn2) {
  __shared__ float ls1[4][96], ls2[4][96];
  const int tid = threadIdx.x;
  const int ri = tid / 96, j = tid - ri * 96;   // row-in-block, channel quad
  const int rg = blockIdx.x * 4 + ri;
  const int b = rg / LROW, l = rg - b * LROW;
  const int h = l / 28, w = l - h * 28;
  const int c0 = j * 4;
  // per-thread weight regs: wl[v][e] = cw[(c0 + (v*4+e)/9 ... )] raw; transpose statically
  float wl[36];
#pragma unroll
  for (int v = 0; v < 9; ++v) {
    f32x4 t = *(const f32x4*)(cw + (size_t)c0 * 9 + v * 4);
    wl[v * 4 + 0] = t[0]; wl[v * 4 + 1] = t[1]; wl[v * 4 + 2] = t[2]; wl[v * 4 + 3] = t[3];
  }
  // weight for channel-offset e (0..3), tap t (0..8) is wl[e*9 + t]
  f32x4 acc = {0.f, 0.f, 0.f, 0.f};
#pragma unroll
  for (int dh = -1; dh <= 1; ++dh) {
    int hh = h + dh;
    if (hh < 0 || hh >= 28) continue;
#pragma unroll
    for (int dw = -1; dw <= 1; ++dw) {
      int ww = w + dw;
      if (ww < 0 || ww >= 28) continue;
      f32x4 xi = *(const f32x4*)(x1 + ((size_t)b * LROW + hh * 28 + ww) * CDIM + c0);
      const int t = (dh + 1) * 3 + (dw + 1);
      acc[0] += xi[0] * wl[0 * 9 + t];
      acc[1] += xi[1] * wl[1 * 9 + t];
      acc[2] += xi[2] * wl[2 * 9 + t];
      acc[3] += xi[3] * wl[3 * 9 + t];
    }
  }
  f32x4 m4 = *(const f32x4*)(bnm + c0), v4 = *(const f32x4*)(bnv + c0);
  f32x4 g4 = *(const f32x4*)(bng + c0), b4 = *(const f32x4*)(bnb + c0);
  f32x4 y;
#pragma unroll
  for (int e = 0; e < 4; ++e)
    y[e] = (acc[e] - m4[e]) * rsqrtf(v4[e] + 1e-5f) * g4[e] + b4[e];
  *(f32x4*)(x2 + (size_t)rg * CDIM + c0) = y;
  ls1[ri][j] = y[0] + y[1] + y[2] + y[3];
  ls2[ri][j] = y[0] * y[0] + y[1] * y[1] + y[2] * y[2] + y[3] * y[3];
  __syncthreads();
  if (j < 32) {
    ls1[ri][j] += ls1[ri][j + 32] + ls1[ri][j + 64];
    ls2[ri][j] += ls2[ri][j + 32] + ls2[ri][j + 64];
  }
  __syncthreads();
  for (int s = 16; s > 0; s >>= 1) {
    if (j < s) { ls1[ri][j] += ls1[ri][j + s]; ls2[ri][j] += ls2[ri][j + s]; }
    __syncthreads();
  }
  const float mean = ls1[ri][0] * (1.f / CDIM);
  const float var = ls2[ri][0] * (1.f / CDIM) - mean * mean;
  const float inv = rsqrtf(var + 1e-5f);
  f32x4 lg = *(const f32x4*)(lng + c0), lb = *(const f32x4*)(lnb + c0);
  short4v ov;
#pragma unroll
  for (int e = 0; e < 4; ++e)
    ov[e] = (short)fbits((y[e] - mean) * inv * lg[e] + lb[e]);
  *(short4v*)((unsigned short*)xn2 + (size_t)rg * CDIM + c0) = ov;
}

extern "C" void kernel_launch(void* const* d_in, const int* in_sizes, int n_in,
                              void* d_out, int out_size, void* d_ws, size_t ws_size,
                              hipStream_t stream) {
  float* out = (float*)d_out;
  static const int EXP[20] = {19267584, 384, 384, 442368, 1152, 588, 2401, 147456, 384, 3456,
                              384, 384, 384, 384, 384, 384, 589824, 1536, 589824, 384};
  const void* p[20];
  bool ok = (n_in == 20);
  int badslot = 30;
  if (ok) {
    bool used[20] = {false};
    for (int i = 0; i < 20 && ok; ++i) {
      int occ = 0;
      for (int j = 0; j < i; ++j) if (EXP[j] == EXP[i]) ++occ;
      int found = -1, seen = 0;
      for (int j = 0; j < 20; ++j) {
        if (in_sizes[j] == EXP[i]) {
          if (seen == occ) { found = j; break; }
          ++seen;
        }
      }
      if (found < 0 || used[found]) { ok = false; badslot = i; break; }
      used[found] = true;
      p[i] = d_in[found];
    }
  }
  const int NOUT = NROWS * CDIM;
  if (!ok) {
    k_fill<<<(NOUT + 255) / 256, 256, 0, stream>>>(out, NOUT, -(2.0f + 0.05f * badslot));
    return;
  }
  const size_t RB = (size_t)NROWS * CDIM;  // 19,267,584 elems
  if (ws_size < RB * 8 + 1024) {
    k_fill<<<(NOUT + 255) / 256, 256, 0, stream>>>(out, NOUT, -5.0f);
    return;
  }
  // ---- workspace plan (peak 8*RB bytes = 154.1 MB, verified) ----
  char* base = (char*)d_ws;
  bf16* xn1 = (bf16*)base;
  bf16* qkvb = (bf16*)(base + RB * 2);
  bf16* attnb = (bf16*)base;
  float* x1 = (float*)(base + RB * 2);
  bf16* wfc1 = (bf16*)(base + RB * 6);
  bf16* wfc2 = (bf16*)(base + RB * 6 + 1179648);
  bf16* xn2 = (bf16*)base;
  bf16* hbuf = (bf16*)(base + RB * 2);
  bf16* wqkv = (bf16*)d_out;                        // d_out scratch, dead before k_convln
  bf16* wproj = (bf16*)d_out + 442368;
  float* biasT = (float*)((char*)d_out + 1179648);  // 196,608 B after the weight scratch

  const float* xin = (const float*)p[0];
  const int noff = 49;

  k_f2b<<<(442368 + 255) / 256, 256, 0, stream>>>((const float*)p[3], wqkv, 442368);
  k_f2b<<<(147456 + 255) / 256, 256, 0, stream>>>((const float*)p[7], wproj, 147456);
  k_biast<<<(NHEADS * 64 * 64 + 255) / 256, 256, 0, stream>>>(
      (const float*)p[5], (const int*)p[6], noff, biasT);

  k_ln_win<<<NROWS, 256, 0, stream>>>(xin, (const float*)p[1], (const float*)p[2], xn1);
  k_gqkv<<<(NROWS / 128) * (QKVD / 128), 256, 0, stream>>>(
      xn1, wqkv, (const float*)p[4], qkvb);
  k_attn2<<<(1024 * NHEADS) / 4, 256, 0, stream>>>(qkvb, biasT, attnb);
  k_f2b<<<(589824 + 255) / 256, 256, 0, stream>>>((const float*)p[16], wfc1, 589824);
  k_f2b<<<(589824 + 255) / 256, 256, 0, stream>>>((const float*)p[18], wfc2, 589824);
  k_gproj<<<(NROWS / 128) * (CDIM / 128), 256, 0, stream>>>(
      attnb, wproj, (const float*)p[8], xin, x1);
  // fused conv+BN+LN: writes x2 -> d_out (residual carrier) and xn2 -> ws base
  k_convln<<<NROWS / 4, 384, 0, stream>>>(
      x1, (const float*)p[9], (const float*)p[10], (const float*)p[11],
      (const float*)p[12], (const float*)p[13], (const float*)p[14],
      (const float*)p[15], out, xn2);
  {
    const int g1 = (MHALF / 128) * (MLPH / 128);   // 2352
    const int g2 = (MHALF / 128) * (CDIM / 64);    // 1176
    k_gfc1<<<g1, 256, 0, stream>>>(xn2, wfc1, (const float*)p[17], hbuf);
    k_gfc2<<<g2, 256, 0, stream>>>(hbuf, wfc2, (const float*)p[19], out);
    k_gfc1<<<g1, 256, 0, stream>>>(xn2 + (size_t)MHALF * CDIM, wfc1, (const float*)p[17], hbuf);
    k_gfc2<<<g2, 256, 0, stream>>>(hbuf, wfc2, (const float*)p[19], out + (size_t)MHALF * CDIM);
  }
}